// Round 13
// baseline (68.209 us; speedup 1.0000x reference)
//
#include <hip/hip_runtime.h>
#include <stdint.h>

#define D_FEAT 128
#define H1 18
#define H2 32
#define EPS 1e-8f

typedef float f32x4 __attribute__((ext_vector_type(4)));
typedef float f32x2 __attribute__((ext_vector_type(2)));

// ---------- prep: x[f32,N,128] -> NORMALIZED fp8-e4m3 [N,128B] ----------
__global__ __launch_bounds__(256) void prep_kernel(
    const float* __restrict__ x,
    uint32_t* __restrict__ xq,   // [N][32] u32 : 4 fp8 per u32
    int n_nodes)
{
    const int lane = threadIdx.x & 63;
    const int sub = lane & 31;
    const int half = lane >> 5;
    const int wavesPerBlock = blockDim.x >> 6;
    const long long wv = (long long)blockIdx.x * wavesPerBlock + (threadIdx.x >> 6);
    const int node = (int)(2 * wv + half);
    if (node >= n_nodes) return;

    const f32x4 v = __builtin_nontemporal_load(
        reinterpret_cast<const f32x4*>(x + (size_t)node * D_FEAT) + sub);
    float ss = v[0] * v[0] + v[1] * v[1] + v[2] * v[2] + v[3] * v[3];
    #pragma unroll
    for (int m = 16; m >= 1; m >>= 1) ss += __shfl_xor(ss, m);
    const float r = 1.0f / fmaxf(sqrtf(ss), EPS);

    int p = 0;
    p = __builtin_amdgcn_cvt_pk_fp8_f32(v[0] * r, v[1] * r, p, false);
    p = __builtin_amdgcn_cvt_pk_fp8_f32(v[2] * r, v[3] * r, p, true);
    xq[(size_t)node * 32 + sub] = (uint32_t)p;
}

// fp8 e4m3 dot of 8 pairs (uint2 = 8 fp8 each), fp32 accumulate
__device__ __forceinline__ float dot8f8(uint2 s, uint2 t) {
    const f32x2 s0 = __builtin_amdgcn_cvt_pk_f32_fp8((int)s.x, false);
    const f32x2 s1 = __builtin_amdgcn_cvt_pk_f32_fp8((int)s.x, true);
    const f32x2 s2 = __builtin_amdgcn_cvt_pk_f32_fp8((int)s.y, false);
    const f32x2 s3 = __builtin_amdgcn_cvt_pk_f32_fp8((int)s.y, true);
    const f32x2 t0 = __builtin_amdgcn_cvt_pk_f32_fp8((int)t.x, false);
    const f32x2 t1 = __builtin_amdgcn_cvt_pk_f32_fp8((int)t.x, true);
    const f32x2 t2 = __builtin_amdgcn_cvt_pk_f32_fp8((int)t.y, false);
    const f32x2 t3 = __builtin_amdgcn_cvt_pk_f32_fp8((int)t.y, true);
    float d;
    d = s0[0] * t0[0];
    d = fmaf(s0[1], t0[1], d);
    d = fmaf(s1[0], t1[0], d);
    d = fmaf(s1[1], t1[1], d);
    d = fmaf(s2[0], t2[0], d);
    d = fmaf(s2[1], t2[1], d);
    d = fmaf(s3[0], t3[0], d);
    d = fmaf(s3[1], t3[1], d);
    return d;
}

// ---------- main: ONE 64-edge burst per wave, ALL 32 fp8 gathers in flight ----------
__global__ __launch_bounds__(256) void edge_kernel(
    const uint2* __restrict__ xq,       // [N][16] (8 fp8 per uint2)
    const int* __restrict__ edge_index, // [2, E]
    const float* __restrict__ edge_attr,
    const float* __restrict__ W1, const float* __restrict__ b1,
    const float* __restrict__ W2, const float* __restrict__ b2,
    float* __restrict__ out, int n_edges)
{
    __shared__ int sIdx[4][64];
    __shared__ int tIdx[4][64];
    __shared__ float dotb[4][64];

    const int lane = threadIdx.x & 63;
    const int w = threadIdx.x >> 6;
    const int g = lane >> 4;
    const int k = lane & 15;
    const long long nBursts = ((long long)n_edges + 63) >> 6;
    const long long burst = (long long)blockIdx.x * 4 + w;
    if (burst >= nBursts) return;

    const f32x4* __restrict__ eav = reinterpret_cast<const f32x4*>(edge_attr);
    const f32x4* __restrict__ W2v = reinterpret_cast<const f32x4*>(W2);
    const f32x4* __restrict__ b2v = reinterpret_cast<const f32x4*>(b2);

    // ---- stage indices (lane = edge) ----
    const long long e = (burst << 6) + lane;
    const bool act = e < (long long)n_edges;
    {
        int sL = 0, tL = 0;
        if (act) {
            sL = edge_index[e];
            tL = edge_index[(long long)n_edges + e];
        }
        sIdx[w][lane] = sL;
        tIdx[w][lane] = tL;
    }

    // ---- issue ALL 32 independent gathers (64 VGPR of data in flight) ----
    uint2 su[16], tu[16];
    #pragma unroll
    for (int s = 0; s < 16; ++s) {
        const int eg = s * 4 + g;
        su[s] = xq[(size_t)sIdx[w][eg] * 16 + k];
        tu[s] = xq[(size_t)tIdx[w][eg] * 16 + k];
    }

    // ---- attr load rides behind the gathers ----
    f32x4 attr = (f32x4)0.f;
    if (act) attr = eav[e];

    // ---- consume in issue order ----
    #pragma unroll
    for (int s = 0; s < 16; ++s) {
        const int eg = s * 4 + g;
        float d = dot8f8(su[s], tu[s]);
        d += __shfl_xor(d, 1);
        d += __shfl_xor(d, 2);
        d += __shfl_xor(d, 4);
        d += __shfl_xor(d, 8);
        if (k == 0) dotb[w][eg] = d;
    }

    const float cosv = dotb[w][lane];

    // ---- per-lane MLP: feats = {attr[0..3], cosv} ----
    float h[H1];
    #pragma unroll
    for (int i = 0; i < H1; ++i) {
        float v = b1[i];
        v = fmaf(attr[0], W1[0 * H1 + i], v);
        v = fmaf(attr[1], W1[1 * H1 + i], v);
        v = fmaf(attr[2], W1[2 * H1 + i], v);
        v = fmaf(attr[3], W1[3 * H1 + i], v);
        v = fmaf(cosv,    W1[4 * H1 + i], v);
        h[i] = fmaxf(v, 0.f);
    }

    if (act) {
        f32x4* op = reinterpret_cast<f32x4*>(out + (size_t)e * H2);
        #pragma unroll
        for (int jg = 0; jg < 8; ++jg) {
            f32x4 a = b2v[jg];
            #pragma unroll
            for (int i = 0; i < H1; ++i)
                a += h[i] * W2v[i * 8 + jg];
            #pragma unroll
            for (int c = 0; c < 4; ++c)
                a[c] = fmaxf(a[c], 0.f);
            op[jg] = a;
        }
    }
}

// ---------- fallback (fp32 direct, known-good from round 1) ----------
__device__ __forceinline__ float mlp_out32(
    const float4 ea, float cosv,
    const float* __restrict__ sW1, const float* __restrict__ sb1,
    const float* __restrict__ sW2, const float* __restrict__ sb2,
    int sub, int base)
{
    const float f[5] = { ea.x, ea.y, ea.z, ea.w, cosv };
    float hval = 0.f;
    if (sub < H1) {
        hval = sb1[sub];
        #pragma unroll
        for (int kk = 0; kk < 5; ++kk) hval = fmaf(f[kk], sW1[kk * H1 + sub], hval);
        hval = fmaxf(hval, 0.f);
    }
    float acc = sb2[sub];
    #pragma unroll
    for (int i = 0; i < H1; ++i)
        acc = fmaf(__shfl(hval, base + i), sW2[i * H2 + sub], acc);
    return fmaxf(acc, 0.f);
}

__global__ __launch_bounds__(256) void edge_encoder_fp32(
    const float* __restrict__ x,
    const int* __restrict__ edge_index,
    const float* __restrict__ edge_attr,
    const float* __restrict__ W1, const float* __restrict__ b1,
    const float* __restrict__ W2, const float* __restrict__ b2,
    float* __restrict__ out, int n_edges)
{
    __shared__ float sW1[5 * H1];
    __shared__ float sb1[H1];
    __shared__ float sW2[H1 * H2];
    __shared__ float sb2[H2];
    for (int i = threadIdx.x; i < 5 * H1; i += blockDim.x) sW1[i] = W1[i];
    for (int i = threadIdx.x; i < H1; i += blockDim.x) sb1[i] = b1[i];
    for (int i = threadIdx.x; i < H1 * H2; i += blockDim.x) sW2[i] = W2[i];
    for (int i = threadIdx.x; i < H2; i += blockDim.x) sb2[i] = b2[i];
    __syncthreads();

    const int lane = threadIdx.x & 63;
    const int sub = lane & 31;
    const int base = lane & 32;
    const int wavesPerBlock = blockDim.x >> 6;
    const int waveId = blockIdx.x * wavesPerBlock + (threadIdx.x >> 6);
    const int totalWaves = gridDim.x * wavesPerBlock;

    for (long long gg = waveId; 2 * gg < (long long)n_edges; gg += totalWaves) {
        const long long e = 2 * gg + (lane >> 5);
        const bool active = (e < (long long)n_edges);
        float dot = 0.f, ss = 0.f, tt = 0.f;
        float4 ea = make_float4(0.f, 0.f, 0.f, 0.f);
        if (active) {
            const int srcN = edge_index[e];
            const int tgtN = edge_index[(long long)n_edges + e];
            const float4 s4 = *reinterpret_cast<const float4*>(
                x + (size_t)srcN * D_FEAT + (size_t)sub * 4);
            const float4 t4 = *reinterpret_cast<const float4*>(
                x + (size_t)tgtN * D_FEAT + (size_t)sub * 4);
            dot = s4.x * t4.x + s4.y * t4.y + s4.z * t4.z + s4.w * t4.w;
            ss  = s4.x * s4.x + s4.y * s4.y + s4.z * s4.z + s4.w * s4.w;
            tt  = t4.x * t4.x + t4.y * t4.y + t4.z * t4.z + t4.w * t4.w;
            ea = *reinterpret_cast<const float4*>(edge_attr + e * 4);
        }
        #pragma unroll
        for (int m = 16; m >= 1; m >>= 1) {
            dot += __shfl_xor(dot, m);
            ss  += __shfl_xor(ss, m);
            tt  += __shfl_xor(tt, m);
        }
        const float cosv = dot / (fmaxf(sqrtf(ss), EPS) * fmaxf(sqrtf(tt), EPS));
        const float o = mlp_out32(ea, cosv, sW1, sb1, sW2, sb2, sub, base);
        if (active) out[e * H2 + sub] = o;
    }
}

extern "C" void kernel_launch(void* const* d_in, const int* in_sizes, int n_in,
                              void* d_out, int out_size, void* d_ws, size_t ws_size,
                              hipStream_t stream) {
    const float* x         = (const float*)d_in[0];
    const int*   edge_idx  = (const int*)d_in[1];
    const float* edge_attr = (const float*)d_in[2];
    const float* W1        = (const float*)d_in[3];
    const float* b1        = (const float*)d_in[4];
    const float* W2        = (const float*)d_in[5];
    const float* b2        = (const float*)d_in[6];
    float* out = (float*)d_out;

    const int n_nodes = in_sizes[0] / D_FEAT;
    const int n_edges = in_sizes[1] / 2;

    const size_t xq_bytes = (size_t)n_nodes * D_FEAT;   // 1 byte per element

    if (ws_size >= xq_bytes) {
        uint32_t* xq = (uint32_t*)d_ws;
        const int block = 256;
        const int prep_grid = (n_nodes + 7) / 8;   // 2 nodes/wave, 8/block
        prep_kernel<<<prep_grid, block, 0, stream>>>(x, xq, n_nodes);

        const long long nBursts = ((long long)n_edges + 63) >> 6;
        const int grid = (int)((nBursts + 3) / 4);   // exactly ONE burst per wave
        edge_kernel<<<grid, block, 0, stream>>>(
            (const uint2*)xq, edge_idx, edge_attr,
            W1, b1, W2, b2, out, n_edges);
    } else {
        edge_encoder_fp32<<<2048, 256, 0, stream>>>(
            x, edge_idx, edge_attr, W1, b1, W2, b2, out, n_edges);
    }
}

// Round 14
// 62.566 us; speedup vs baseline: 1.0902x; 1.0902x over previous
//
#include <hip/hip_runtime.h>
#include <stdint.h>

#define D_FEAT 128
#define H1 18
#define H2 32
#define EPS 1e-8f

typedef float f32x4 __attribute__((ext_vector_type(4)));
typedef float f32x2 __attribute__((ext_vector_type(2)));

// ---------- prep: x[f32,N,128] -> NORMALIZED fp8-e4m3 [N,128B] ----------
__global__ __launch_bounds__(256) void prep_kernel(
    const float* __restrict__ x,
    uint32_t* __restrict__ xq,   // [N][32] u32 : 4 fp8 per u32
    int n_nodes)
{
    const int lane = threadIdx.x & 63;
    const int sub = lane & 31;
    const int half = lane >> 5;
    const int wavesPerBlock = blockDim.x >> 6;
    const long long wv = (long long)blockIdx.x * wavesPerBlock + (threadIdx.x >> 6);
    const int node = (int)(2 * wv + half);
    if (node >= n_nodes) return;

    const f32x4 v = __builtin_nontemporal_load(
        reinterpret_cast<const f32x4*>(x + (size_t)node * D_FEAT) + sub);
    float ss = v[0] * v[0] + v[1] * v[1] + v[2] * v[2] + v[3] * v[3];
    #pragma unroll
    for (int m = 16; m >= 1; m >>= 1) ss += __shfl_xor(ss, m);
    const float r = 1.0f / fmaxf(sqrtf(ss), EPS);

    int p = 0;
    p = __builtin_amdgcn_cvt_pk_fp8_f32(v[0] * r, v[1] * r, p, false);
    p = __builtin_amdgcn_cvt_pk_fp8_f32(v[2] * r, v[3] * r, p, true);
    xq[(size_t)node * 32 + sub] = (uint32_t)p;
}

// fp8 e4m3 dot of 16 pairs (uint4 = 16 fp8 each), fp32 accumulate
__device__ __forceinline__ float dot16f8(uint4 s, uint4 t) {
    float d = 0.f;
    #define TERM(SW, TW)                                                   \
        {                                                                  \
            const f32x2 a0 = __builtin_amdgcn_cvt_pk_f32_fp8((int)(SW), false); \
            const f32x2 a1 = __builtin_amdgcn_cvt_pk_f32_fp8((int)(SW), true);  \
            const f32x2 c0 = __builtin_amdgcn_cvt_pk_f32_fp8((int)(TW), false); \
            const f32x2 c1 = __builtin_amdgcn_cvt_pk_f32_fp8((int)(TW), true);  \
            d = fmaf(a0[0], c0[0], d);                                     \
            d = fmaf(a0[1], c0[1], d);                                     \
            d = fmaf(a1[0], c1[0], d);                                     \
            d = fmaf(a1[1], c1[1], d);                                     \
        }
    TERM(s.x, t.x)
    TERM(s.y, t.y)
    TERM(s.z, t.z)
    TERM(s.w, t.w)
    #undef TERM
    return d;
}

// ---------- main: ONE 64-edge burst/wave, 8 lanes/row, ALL 16 uint4 gathers fenced in flight ----------
__global__ __launch_bounds__(256) void edge_kernel(
    const uint4* __restrict__ xq,       // [N][8] (16 fp8 per uint4)
    const int* __restrict__ edge_index, // [2, E]
    const float* __restrict__ edge_attr,
    const float* __restrict__ W1, const float* __restrict__ b1,
    const float* __restrict__ W2, const float* __restrict__ b2,
    float* __restrict__ out, int n_edges)
{
    __shared__ int sIdx[4][64];
    __shared__ int tIdx[4][64];
    __shared__ float dotb[4][64];

    const int lane = threadIdx.x & 63;
    const int w = threadIdx.x >> 6;
    const int g = lane >> 3;          // 8 edges per instruction step (0..7)
    const int k = lane & 7;           // lane within 8-lane row group
    const long long nBursts = ((long long)n_edges + 63) >> 6;
    const long long burst = (long long)blockIdx.x * 4 + w;
    if (burst >= nBursts) return;

    const f32x4* __restrict__ eav = reinterpret_cast<const f32x4*>(edge_attr);
    const f32x4* __restrict__ W2v = reinterpret_cast<const f32x4*>(W2);
    const f32x4* __restrict__ b2v = reinterpret_cast<const f32x4*>(b2);

    // ---- stage indices (lane = edge) ----
    const long long e = (burst << 6) + lane;
    const bool act = e < (long long)n_edges;
    {
        int sL = 0, tL = 0;
        if (act) {
            sL = edge_index[e];
            tL = edge_index[(long long)n_edges + e];
        }
        sIdx[w][lane] = sL;
        tIdx[w][lane] = tL;
    }

    // ---- issue ALL 16 row-gathers (16B/lane each; 256B/lane in flight) ----
    uint4 su[8], tu[8];
    #pragma unroll
    for (int s = 0; s < 8; ++s) {
        const int eg = s * 8 + g;
        su[s] = xq[(size_t)sIdx[w][eg] * 8 + k];
        tu[s] = xq[(size_t)tIdx[w][eg] * 8 + k];
    }
    f32x4 attr = (f32x4)0.f;
    if (act) attr = eav[e];

    // hard fence: nothing below may be hoisted above; loads stay issued-early
    __builtin_amdgcn_sched_barrier(0);

    // ---- consume: dot16 + 3-step butterfly over 8 lanes ----
    #pragma unroll
    for (int s = 0; s < 8; ++s) {
        const int eg = s * 8 + g;
        float d = dot16f8(su[s], tu[s]);
        d += __shfl_xor(d, 1);
        d += __shfl_xor(d, 2);
        d += __shfl_xor(d, 4);
        if (k == 0) dotb[w][eg] = d;
    }

    const float cosv = dotb[w][lane];

    // ---- per-lane MLP: feats = {attr[0..3], cosv} ----
    float h[H1];
    #pragma unroll
    for (int i = 0; i < H1; ++i) {
        float v = b1[i];
        v = fmaf(attr[0], W1[0 * H1 + i], v);
        v = fmaf(attr[1], W1[1 * H1 + i], v);
        v = fmaf(attr[2], W1[2 * H1 + i], v);
        v = fmaf(attr[3], W1[3 * H1 + i], v);
        v = fmaf(cosv,    W1[4 * H1 + i], v);
        h[i] = fmaxf(v, 0.f);
    }

    if (act) {
        f32x4* op = reinterpret_cast<f32x4*>(out + (size_t)e * H2);
        #pragma unroll
        for (int jg = 0; jg < 8; ++jg) {
            f32x4 a = b2v[jg];
            #pragma unroll
            for (int i = 0; i < H1; ++i)
                a += h[i] * W2v[i * 8 + jg];
            #pragma unroll
            for (int c = 0; c < 4; ++c)
                a[c] = fmaxf(a[c], 0.f);
            op[jg] = a;
        }
    }
}

// ---------- fallback (fp32 direct, known-good from round 1) ----------
__device__ __forceinline__ float mlp_out32(
    const float4 ea, float cosv,
    const float* __restrict__ sW1, const float* __restrict__ sb1,
    const float* __restrict__ sW2, const float* __restrict__ sb2,
    int sub, int base)
{
    const float f[5] = { ea.x, ea.y, ea.z, ea.w, cosv };
    float hval = 0.f;
    if (sub < H1) {
        hval = sb1[sub];
        #pragma unroll
        for (int kk = 0; kk < 5; ++kk) hval = fmaf(f[kk], sW1[kk * H1 + sub], hval);
        hval = fmaxf(hval, 0.f);
    }
    float acc = sb2[sub];
    #pragma unroll
    for (int i = 0; i < H1; ++i)
        acc = fmaf(__shfl(hval, base + i), sW2[i * H2 + sub], acc);
    return fmaxf(acc, 0.f);
}

__global__ __launch_bounds__(256) void edge_encoder_fp32(
    const float* __restrict__ x,
    const int* __restrict__ edge_index,
    const float* __restrict__ edge_attr,
    const float* __restrict__ W1, const float* __restrict__ b1,
    const float* __restrict__ W2, const float* __restrict__ b2,
    float* __restrict__ out, int n_edges)
{
    __shared__ float sW1[5 * H1];
    __shared__ float sb1[H1];
    __shared__ float sW2[H1 * H2];
    __shared__ float sb2[H2];
    for (int i = threadIdx.x; i < 5 * H1; i += blockDim.x) sW1[i] = W1[i];
    for (int i = threadIdx.x; i < H1; i += blockDim.x) sb1[i] = b1[i];
    for (int i = threadIdx.x; i < H1 * H2; i += blockDim.x) sW2[i] = W2[i];
    for (int i = threadIdx.x; i < H2; i += blockDim.x) sb2[i] = b2[i];
    __syncthreads();

    const int lane = threadIdx.x & 63;
    const int sub = lane & 31;
    const int base = lane & 32;
    const int wavesPerBlock = blockDim.x >> 6;
    const int waveId = blockIdx.x * wavesPerBlock + (threadIdx.x >> 6);
    const int totalWaves = gridDim.x * wavesPerBlock;

    for (long long gg = waveId; 2 * gg < (long long)n_edges; gg += totalWaves) {
        const long long e = 2 * gg + (lane >> 5);
        const bool active = (e < (long long)n_edges);
        float dot = 0.f, ss = 0.f, tt = 0.f;
        float4 ea = make_float4(0.f, 0.f, 0.f, 0.f);
        if (active) {
            const int srcN = edge_index[e];
            const int tgtN = edge_index[(long long)n_edges + e];
            const float4 s4 = *reinterpret_cast<const float4*>(
                x + (size_t)srcN * D_FEAT + (size_t)sub * 4);
            const float4 t4 = *reinterpret_cast<const float4*>(
                x + (size_t)tgtN * D_FEAT + (size_t)sub * 4);
            dot = s4.x * t4.x + s4.y * t4.y + s4.z * t4.z + s4.w * t4.w;
            ss  = s4.x * s4.x + s4.y * s4.y + s4.z * s4.z + s4.w * s4.w;
            tt  = t4.x * t4.x + t4.y * t4.y + t4.z * t4.z + t4.w * t4.w;
            ea = *reinterpret_cast<const float4*>(edge_attr + e * 4);
        }
        #pragma unroll
        for (int m = 16; m >= 1; m >>= 1) {
            dot += __shfl_xor(dot, m);
            ss  += __shfl_xor(ss, m);
            tt  += __shfl_xor(tt, m);
        }
        const float cosv = dot / (fmaxf(sqrtf(ss), EPS) * fmaxf(sqrtf(tt), EPS));
        const float o = mlp_out32(ea, cosv, sW1, sb1, sW2, sb2, sub, base);
        if (active) out[e * H2 + sub] = o;
    }
}

extern "C" void kernel_launch(void* const* d_in, const int* in_sizes, int n_in,
                              void* d_out, int out_size, void* d_ws, size_t ws_size,
                              hipStream_t stream) {
    const float* x         = (const float*)d_in[0];
    const int*   edge_idx  = (const int*)d_in[1];
    const float* edge_attr = (const float*)d_in[2];
    const float* W1        = (const float*)d_in[3];
    const float* b1        = (const float*)d_in[4];
    const float* W2        = (const float*)d_in[5];
    const float* b2        = (const float*)d_in[6];
    float* out = (float*)d_out;

    const int n_nodes = in_sizes[0] / D_FEAT;
    const int n_edges = in_sizes[1] / 2;

    const size_t xq_bytes = (size_t)n_nodes * D_FEAT;   // 1 byte per element

    if (ws_size >= xq_bytes) {
        uint32_t* xq = (uint32_t*)d_ws;
        const int block = 256;
        const int prep_grid = (n_nodes + 7) / 8;   // 2 nodes/wave, 8/block
        prep_kernel<<<prep_grid, block, 0, stream>>>(x, xq, n_nodes);

        const long long nBursts = ((long long)n_edges + 63) >> 6;
        const int grid = (int)((nBursts + 3) / 4);   // exactly ONE burst per wave
        edge_kernel<<<grid, block, 0, stream>>>(
            (const uint4*)xq, edge_idx, edge_attr,
            W1, b1, W2, b2, out, n_edges);
    } else {
        edge_encoder_fp32<<<2048, 256, 0, stream>>>(
            x, edge_idx, edge_attr, W1, b1, W2, b2, out, n_edges);
    }
}